// Round 1
// baseline (81.181 us; speedup 1.0000x reference)
//
#include <hip/hip_runtime.h>

#define BATCH 4
#define DCH   256
#define H8    48
#define W8    64
#define SPAT  3072   // H8*W8
#define NL    41

// Diamond displacement set, enumeration order: y in [-4,4], x in [|y|-4, 4-|y|]
__constant__ float c_ys[NL] = {
    -4,
    -3,-3,-3,
    -2,-2,-2,-2,-2,
    -1,-1,-1,-1,-1,-1,-1,
     0, 0, 0, 0, 0, 0, 0, 0, 0,
     1, 1, 1, 1, 1, 1, 1,
     2, 2, 2, 2, 2,
     3, 3, 3,
     4
};
__constant__ float c_xs[NL] = {
     0,
    -1, 0, 1,
    -2,-1, 0, 1, 2,
    -3,-2,-1, 0, 1, 2, 3,
    -4,-3,-2,-1, 0, 1, 2, 3, 4,
    -3,-2,-1, 0, 1, 2, 3,
    -2,-1, 0, 1, 2,
    -1, 0, 1,
     0
};

// (B, D, S) -> (B, S, D) channel-last transpose for both feats.
// feat1 additionally scaled by 1/sqrt(D) = 1/16.
__global__ __launch_bounds__(256) void transpose_kernel(
        const float* __restrict__ feat1, const float* __restrict__ feat2,
        float* __restrict__ f1t, float* __restrict__ f20) {
    __shared__ float tile[64][65];
    int bid = blockIdx.x;
    int which = bid / 768;          // 0: feat1, 1: feat2
    int rem   = bid % 768;
    int b   = rem / 192;
    int r2  = rem % 192;
    int d0  = (r2 / 48) * 64;
    int s0  = (r2 % 48) * 64;
    const float* in  = which ? feat2 : feat1;
    float*       out = which ? f20   : f1t;
    float scale = which ? 1.0f : 0.0625f;
    int tx = threadIdx.x & 63, ty = threadIdx.x >> 6;
    #pragma unroll
    for (int r = 0; r < 16; ++r) {
        int dl = r * 4 + ty;
        tile[dl][tx] = in[(size_t)(b * DCH + d0 + dl) * SPAT + s0 + tx] * scale;
    }
    __syncthreads();
    #pragma unroll
    for (int r = 0; r < 16; ++r) {
        int sl = r * 4 + ty;
        out[(size_t)(b * SPAT + s0 + sl) * DCH + d0 + tx] = tile[tx][sl];
    }
}

// Build pooled feat2 pyramid levels 1..3 (channel-last), averaging 2^k x 2^k.
__global__ __launch_bounds__(256) void pyramid_kernel(
        const float* __restrict__ f20, float* __restrict__ f21,
        float* __restrict__ f22, float* __restrict__ f23) {
    int idx = blockIdx.x * 256 + threadIdx.x;
    int k, e; float* out;
    if (idx < 196608)      { k = 1; e = idx;          out = f21; }
    else if (idx < 245760) { k = 2; e = idx - 196608; out = f22; }
    else if (idx < 258048) { k = 3; e = idx - 245760; out = f23; }
    else return;
    int s  = 1 << k;
    int wk = W8 >> k, hk = H8 >> k;
    int d4 = e & 63;
    int r  = e >> 6;
    int x  = r % wk; r /= wk;
    int y  = r % hk;
    int b  = r / hk;
    float4 acc = make_float4(0.f, 0.f, 0.f, 0.f);
    for (int yy = 0; yy < s; ++yy)
        for (int xx = 0; xx < s; ++xx) {
            const float4 v = *(const float4*)(f20 +
                (size_t)((b * H8 + y * s + yy) * W8 + x * s + xx) * DCH + d4 * 4);
            acc.x += v.x; acc.y += v.y; acc.z += v.z; acc.w += v.w;
        }
    float inv = 1.0f / (float)(s * s);
    acc.x *= inv; acc.y *= inv; acc.z *= inv; acc.w *= inv;
    *(float4*)(out + (size_t)(((b * hk + y) * wk + x) * DCH) + d4 * 4) = acc;
}

// Main: one wave per (b,i,j,k). Distinct-corner-cell dot products, then
// 41 bilinear combines (lanes 0..40).
__global__ __launch_bounds__(256) void lookup_kernel(
        const float* __restrict__ f1t,
        const float* __restrict__ f20, const float* __restrict__ f21,
        const float* __restrict__ f22, const float* __restrict__ f23,
        const float* __restrict__ flow, float* __restrict__ out) {
    __shared__ float cells[4][16];
    int bid = blockIdx.x;            // b*3072 + i*64 + j
    int b = bid / SPAT;
    int sp = bid % SPAT;
    int i = sp >> 6;
    int j = sp & 63;
    int k    = threadIdx.x >> 6;     // wave id == pyramid level
    int lane = threadIdx.x & 63;

    const float* f2lv[4] = {f20, f21, f22, f23};
    const float* f2k = f2lv[k];
    int hk = H8 >> k, wk = W8 >> k;
    float sc = (float)(1 << k);
    float rx = (float)(wk - 1) / (512.0f / sc);
    float ry = (float)(hk - 1) / (384.0f / sc);

    float fy = flow[i * W8 + j];
    float fx = flow[SPAT + i * W8 + j];
    float base_x = ((float)j + fx) / sc;
    float base_y = ((float)i + fy) / sc;

    int x0lo = (int)floorf((base_x - 4.0f) * rx);
    int x0hi = (int)floorf((base_x + 4.0f) * rx);
    int y0lo = (int)floorf((base_y - 4.0f) * ry);
    int y0hi = (int)floorf((base_y + 4.0f) * ry);
    int nx = x0hi - x0lo + 2;        // <= 3 (span 8*rx < 1)
    int ny = y0hi - y0lo + 2;        // <= 3

    const float4 f1 = *(const float4*)(f1t + (size_t)bid * DCH + lane * 4);

    for (int cy = 0; cy < ny; ++cy) {
        int y = y0lo + cy;
        for (int cx = 0; cx < nx; ++cx) {
            int x = x0lo + cx;
            float sdot = 0.0f;
            if (y >= 0 && y < hk && x >= 0 && x < wk) {   // wave-uniform
                const float4 v = *(const float4*)(f2k +
                    (size_t)((b * hk + y) * wk + x) * DCH + lane * 4);
                sdot = f1.x * v.x + f1.y * v.y + f1.z * v.z + f1.w * v.w;
                #pragma unroll
                for (int off = 32; off > 0; off >>= 1)
                    sdot += __shfl_xor(sdot, off, 64);
            }
            if (lane == 0) cells[k][cy * 4 + cx] = sdot;
        }
    }
    __syncthreads();

    if (lane < NL) {
        float px = (base_x + c_xs[lane]) * rx;
        float py = (base_y + c_ys[lane]) * ry;
        float x0f = floorf(px), y0f = floorf(py);
        float tx = px - x0f, ty = py - y0f;
        int cx0 = (int)x0f - x0lo;
        int cy0 = (int)y0f - y0lo;
        float d00 = cells[k][cy0 * 4 + cx0];
        float d01 = cells[k][cy0 * 4 + cx0 + 1];
        float d10 = cells[k][cy0 * 4 + cx0 + 4];
        float d11 = cells[k][cy0 * 4 + cx0 + 5];
        float v = d00 * (1.0f - tx) * (1.0f - ty) + d01 * tx * (1.0f - ty)
                + d10 * (1.0f - tx) * ty          + d11 * tx * ty;
        out[(size_t)((b * NL + lane) * 4 + k) * SPAT + i * W8 + j] = v;
    }
}

extern "C" void kernel_launch(void* const* d_in, const int* in_sizes, int n_in,
                              void* d_out, int out_size, void* d_ws, size_t ws_size,
                              hipStream_t stream) {
    const float* feat1 = (const float*)d_in[0];
    const float* feat2 = (const float*)d_in[1];
    const float* flow  = (const float*)d_in[2];
    float* out = (float*)d_out;
    float* ws  = (float*)d_ws;

    float* f1t = ws;                   // 3,145,728 floats
    float* f20 = f1t + 3145728;        // 3,145,728
    float* f21 = f20 + 3145728;        //   786,432
    float* f22 = f21 + 786432;         //   196,608
    float* f23 = f22 + 196608;         //    49,152  (total ~29.3 MB)

    hipLaunchKernelGGL(transpose_kernel, dim3(1536), dim3(256), 0, stream,
                       feat1, feat2, f1t, f20);
    hipLaunchKernelGGL(pyramid_kernel, dim3(1008), dim3(256), 0, stream,
                       f20, f21, f22, f23);
    hipLaunchKernelGGL(lookup_kernel, dim3(12288), dim3(256), 0, stream,
                       f1t, f20, f21, f22, f23, flow, out);
}

// Round 2
// 69.851 us; speedup vs baseline: 1.1622x; 1.1622x over previous
//
#include <hip/hip_runtime.h>

#define H8    48
#define W8    64
#define SPAT  3072   // H8*W8
#define NL    41

// Diamond displacement set, enumeration order: y in [-4,4], x in [|y|-4, 4-|y|]
__constant__ float c_ys[NL] = {
    -4,
    -3,-3,-3,
    -2,-2,-2,-2,-2,
    -1,-1,-1,-1,-1,-1,-1,
     0, 0, 0, 0, 0, 0, 0, 0, 0,
     1, 1, 1, 1, 1, 1, 1,
     2, 2, 2, 2, 2,
     3, 3, 3,
     4
};
__constant__ float c_xs[NL] = {
     0,
    -1, 0, 1,
    -2,-1, 0, 1, 2,
    -3,-2,-1, 0, 1, 2, 3,
    -4,-3,-2,-1, 0, 1, 2, 3, 4,
    -3,-2,-1, 0, 1, 2, 3,
    -2,-1, 0, 1, 2,
    -1, 0, 1,
     0
};

// (B, D, S) -> (B, S, D) channel-last transpose for feat2 only.
__global__ __launch_bounds__(256) void transpose_kernel(
        const float* __restrict__ feat2, float* __restrict__ f20) {
    __shared__ float tile[64][65];
    int bid = blockIdx.x;           // 768 = 4b * 4dgrp * 48sgrp
    int b   = bid / 192;
    int r2  = bid % 192;
    int d0  = (r2 / 48) * 64;
    int s0  = (r2 % 48) * 64;
    int tx = threadIdx.x & 63, ty = threadIdx.x >> 6;
    #pragma unroll
    for (int r = 0; r < 16; ++r) {
        int dl = r * 4 + ty;
        tile[dl][tx] = feat2[(size_t)(b * 256 + d0 + dl) * SPAT + s0 + tx];
    }
    __syncthreads();
    #pragma unroll
    for (int r = 0; r < 16; ++r) {
        int sl = r * 4 + ty;
        f20[(size_t)(b * SPAT + s0 + sl) * 256 + d0 + tx] = tile[tx][sl];
    }
}

// Fused pyramid: build channel-last L1/L2/L3 from f20 reading it once.
// Block covers an 8x8 spatial tile of f20 (one L3 cell); 256 threads =
// 4 row-pair parts x 64 channel-quads.
__global__ __launch_bounds__(256) void pyramid_kernel(
        const float* __restrict__ f20, float* __restrict__ f21,
        float* __restrict__ f22, float* __restrict__ f23) {
    __shared__ float4 s1[16][64];   // [L1 cell (part*4+cx)][ch4] raw 2x2 sums
    int bid = blockIdx.x;           // b*48 + sy*8 + sx
    int b  = bid / 48;
    int r  = bid % 48;
    int sy = r >> 3, sx = r & 7;
    int ch4  = threadIdx.x & 63;
    int part = threadIdx.x >> 6;    // 0..3 -> raw rows {2part, 2part+1}

    #pragma unroll
    for (int cx = 0; cx < 4; ++cx) {
        float4 acc = make_float4(0.f, 0.f, 0.f, 0.f);
        #pragma unroll
        for (int rr = 0; rr < 2; ++rr)
            #pragma unroll
            for (int cc = 0; cc < 2; ++cc) {
                int Y = sy * 8 + part * 2 + rr;
                int X = sx * 8 + cx * 2 + cc;
                const float4 v = *(const float4*)(f20 +
                    (size_t)((b * H8 + Y) * W8 + X) * 256 + ch4 * 4);
                acc.x += v.x; acc.y += v.y; acc.z += v.z; acc.w += v.w;
            }
        s1[part * 4 + cx][ch4] = acc;
        float4 o = make_float4(acc.x * 0.25f, acc.y * 0.25f, acc.z * 0.25f, acc.w * 0.25f);
        *(float4*)(f21 + (size_t)((b * 24 + sy * 4 + part) * 32 + sx * 4 + cx) * 256 + ch4 * 4) = o;
    }
    __syncthreads();
    if (part == 0) {
        float4 g[16];
        #pragma unroll
        for (int c = 0; c < 16; ++c) g[c] = s1[c][ch4];
        float4 tot = make_float4(0.f, 0.f, 0.f, 0.f);
        #pragma unroll
        for (int py = 0; py < 2; ++py)
            #pragma unroll
            for (int px = 0; px < 2; ++px) {
                float4 a = g[(2*py)*4 + 2*px],     bb = g[(2*py)*4 + 2*px + 1];
                float4 c = g[(2*py+1)*4 + 2*px],   d  = g[(2*py+1)*4 + 2*px + 1];
                float4 s = make_float4(a.x+bb.x+c.x+d.x, a.y+bb.y+c.y+d.y,
                                       a.z+bb.z+c.z+d.z, a.w+bb.w+c.w+d.w);
                tot.x += s.x; tot.y += s.y; tot.z += s.z; tot.w += s.w;
                float4 o = make_float4(s.x*0.0625f, s.y*0.0625f, s.z*0.0625f, s.w*0.0625f);
                *(float4*)(f22 + (size_t)((b * 12 + sy * 2 + py) * 16 + sx * 2 + px) * 256 + ch4 * 4) = o;
            }
        float4 o = make_float4(tot.x*0.015625f, tot.y*0.015625f, tot.z*0.015625f, tot.w*0.015625f);
        *(float4*)(f23 + (size_t)((b * 6 + sy) * 8 + sx) * 256 + ch4 * 4) = o;
    }
}

// Main: block = (b, i, 16-pixel group). 4 waves = 4 levels; 4 lanes/pixel,
// each lane owns 64 channels of f1 in registers. 3x3 candidate cells per
// pixel, 2-step shfl reduce, LDS-staged epilogue with coalesced stores.
__global__ __launch_bounds__(256) void lookup_kernel(
        const float* __restrict__ feat1,   // (B,256,48,64) original layout
        const float* __restrict__ f20, const float* __restrict__ f21,
        const float* __restrict__ f22, const float* __restrict__ f23,
        const float* __restrict__ flow, float* __restrict__ out) {
    __shared__ float dots[4][16][9];
    __shared__ float mbx[4][16], mby[4][16];
    __shared__ int   mx0[4][16], my0[4][16];

    int bid = blockIdx.x;            // b*192 + i*4 + jg
    int b  = bid / 192;
    int r  = bid % 192;
    int i  = r >> 2;
    int jg = r & 3;
    int k    = threadIdx.x >> 6;     // wave id == pyramid level
    int lane = threadIdx.x & 63;
    int p = lane >> 2;               // pixel in group (0..15)
    int l = lane & 3;                // channel quarter (0..3)
    int j = jg * 16 + p;

    const float* f2lv[4] = {f20, f21, f22, f23};
    const float* f2k = f2lv[k];
    int hk = H8 >> k, wk = W8 >> k;
    float inv_sc = 1.0f / (float)(1 << k);
    float rx = (float)(wk - 1) / (512.0f * inv_sc);
    float ry = (float)(hk - 1) / (384.0f * inv_sc);

    float fy = flow[i * W8 + j];
    float fx = flow[SPAT + i * W8 + j];
    float base_x = ((float)j + fx) * inv_sc;
    float base_y = ((float)i + fy) * inv_sc;
    int x0lo = (int)floorf((base_x - 4.0f) * rx);
    int y0lo = (int)floorf((base_y - 4.0f) * ry);

    // f1 channels l*64 .. l*64+63 into registers (strided scalar loads).
    float f1r[64];
    const float* f1p = feat1 + ((size_t)(b * 256 + l * 64) * H8 + i) * W8 + j;
    #pragma unroll
    for (int c = 0; c < 64; ++c)
        f1r[c] = f1p[(size_t)c * SPAT];

    #pragma unroll
    for (int cy = 0; cy < 3; ++cy) {
        int y = y0lo + cy;
        #pragma unroll
        for (int cx = 0; cx < 3; ++cx) {
            int x = x0lo + cx;
            float acc = 0.0f;
            if (y >= 0 && y < hk && x >= 0 && x < wk) {
                const float* f2p = f2k + ((size_t)(b * hk + y) * wk + x) * 256 + l * 64;
                #pragma unroll
                for (int m = 0; m < 16; ++m) {
                    const float4 v = *(const float4*)(f2p + m * 4);
                    acc += v.x * f1r[m*4+0] + v.y * f1r[m*4+1]
                         + v.z * f1r[m*4+2] + v.w * f1r[m*4+3];
                }
            }
            acc += __shfl_xor(acc, 1, 64);
            acc += __shfl_xor(acc, 2, 64);
            if (l == 0) dots[k][p][cy * 3 + cx] = acc;
        }
    }
    if (l == 0) {
        mbx[k][p] = base_x;
        mby[k][p] = base_y;
        mx0[k][p] = x0lo;
        my0[k][p] = y0lo;
    }
    __syncthreads();

    // Epilogue: 41*4*16 = 2624 outputs, coalesced (p fastest).
    for (int t = threadIdx.x; t < NL * 4 * 16; t += 256) {
        int p2 = t & 15;
        int lk = t >> 4;
        int kk = lk & 3;
        int ld = lk >> 2;
        float sc2 = (float)(1 << kk);
        float rx2 = (float)((W8 >> kk) - 1) / (512.0f / sc2);
        float ry2 = (float)((H8 >> kk) - 1) / (384.0f / sc2);
        float px = (mbx[kk][p2] + c_xs[ld]) * rx2;
        float py = (mby[kk][p2] + c_ys[ld]) * ry2;
        float x0f = floorf(px), y0f = floorf(py);
        float tx = px - x0f, ty = py - y0f;
        int cx0 = (int)x0f - mx0[kk][p2];
        int cy0 = (int)y0f - my0[kk][p2];
        const float* dp = &dots[kk][p2][cy0 * 3 + cx0];
        float d00 = dp[0], d01 = dp[1], d10 = dp[3], d11 = dp[4];
        float v = d00 * (1.0f - tx) * (1.0f - ty) + d01 * tx * (1.0f - ty)
                + d10 * (1.0f - tx) * ty          + d11 * tx * ty;
        out[(size_t)((b * NL + ld) * 4 + kk) * SPAT + i * W8 + jg * 16 + p2] = v * 0.0625f;
    }
}

extern "C" void kernel_launch(void* const* d_in, const int* in_sizes, int n_in,
                              void* d_out, int out_size, void* d_ws, size_t ws_size,
                              hipStream_t stream) {
    const float* feat1 = (const float*)d_in[0];
    const float* feat2 = (const float*)d_in[1];
    const float* flow  = (const float*)d_in[2];
    float* out = (float*)d_out;
    float* ws  = (float*)d_ws;

    float* f20 = ws;                   // 3,145,728 floats
    float* f21 = f20 + 3145728;        //   786,432
    float* f22 = f21 + 786432;         //   196,608
    float* f23 = f22 + 196608;         //    49,152   (total ~16.7 MB)

    hipLaunchKernelGGL(transpose_kernel, dim3(768), dim3(256), 0, stream, feat2, f20);
    hipLaunchKernelGGL(pyramid_kernel, dim3(192), dim3(256), 0, stream,
                       f20, f21, f22, f23);
    hipLaunchKernelGGL(lookup_kernel, dim3(768), dim3(256), 0, stream,
                       feat1, f20, f21, f22, f23, flow, out);
}

// Round 3
// 41.765 us; speedup vs baseline: 1.9438x; 1.6725x over previous
//
#include <hip/hip_runtime.h>

#define H8    48
#define W8    64
#define SPAT  3072   // H8*W8
#define NL    41

// Diamond displacement set, enumeration order: y in [-4,4], x in [|y|-4, 4-|y|]
__constant__ float c_ys[NL] = {
    -4,
    -3,-3,-3,
    -2,-2,-2,-2,-2,
    -1,-1,-1,-1,-1,-1,-1,
     0, 0, 0, 0, 0, 0, 0, 0, 0,
     1, 1, 1, 1, 1, 1, 1,
     2, 2, 2, 2, 2,
     3, 3, 3,
     4
};
__constant__ float c_xs[NL] = {
     0,
    -1, 0, 1,
    -2,-1, 0, 1, 2,
    -3,-2,-1, 0, 1, 2, 3,
    -4,-3,-2,-1, 0, 1, 2, 3, 4,
    -3,-2,-1, 0, 1, 2, 3,
    -2,-1, 0, 1, 2,
    -1, 0, 1,
     0
};

// (B, D, S) -> (B, S, D) channel-last transpose for feat2 only.
__global__ __launch_bounds__(256) void transpose_kernel(
        const float* __restrict__ feat2, float* __restrict__ f20) {
    __shared__ float tile[64][65];
    int bid = blockIdx.x;           // 768 = 4b * 4dgrp * 48sgrp
    int b   = bid / 192;
    int r2  = bid % 192;
    int d0  = (r2 / 48) * 64;
    int s0  = (r2 % 48) * 64;
    int tx = threadIdx.x & 63, ty = threadIdx.x >> 6;
    #pragma unroll
    for (int r = 0; r < 16; ++r) {
        int dl = r * 4 + ty;
        tile[dl][tx] = feat2[(size_t)(b * 256 + d0 + dl) * SPAT + s0 + tx];
    }
    __syncthreads();
    #pragma unroll
    for (int r = 0; r < 16; ++r) {
        int sl = r * 4 + ty;
        f20[(size_t)(b * SPAT + s0 + sl) * 256 + d0 + tx] = tile[tx][sl];
    }
}

// Fused pyramid: build channel-last L1/L2/L3 from f20 reading it once.
__global__ __launch_bounds__(256) void pyramid_kernel(
        const float* __restrict__ f20, float* __restrict__ f21,
        float* __restrict__ f22, float* __restrict__ f23) {
    __shared__ float4 s1[16][64];   // [L1 cell (part*4+cx)][ch4] raw 2x2 sums
    int bid = blockIdx.x;           // b*48 + sy*8 + sx
    int b  = bid / 48;
    int r  = bid % 48;
    int sy = r >> 3, sx = r & 7;
    int ch4  = threadIdx.x & 63;
    int part = threadIdx.x >> 6;    // 0..3 -> raw rows {2part, 2part+1}

    #pragma unroll
    for (int cx = 0; cx < 4; ++cx) {
        float4 acc = make_float4(0.f, 0.f, 0.f, 0.f);
        #pragma unroll
        for (int rr = 0; rr < 2; ++rr)
            #pragma unroll
            for (int cc = 0; cc < 2; ++cc) {
                int Y = sy * 8 + part * 2 + rr;
                int X = sx * 8 + cx * 2 + cc;
                const float4 v = *(const float4*)(f20 +
                    (size_t)((b * H8 + Y) * W8 + X) * 256 + ch4 * 4);
                acc.x += v.x; acc.y += v.y; acc.z += v.z; acc.w += v.w;
            }
        s1[part * 4 + cx][ch4] = acc;
        float4 o = make_float4(acc.x * 0.25f, acc.y * 0.25f, acc.z * 0.25f, acc.w * 0.25f);
        *(float4*)(f21 + (size_t)((b * 24 + sy * 4 + part) * 32 + sx * 4 + cx) * 256 + ch4 * 4) = o;
    }
    __syncthreads();
    if (part == 0) {
        float4 g[16];
        #pragma unroll
        for (int c = 0; c < 16; ++c) g[c] = s1[c][ch4];
        float4 tot = make_float4(0.f, 0.f, 0.f, 0.f);
        #pragma unroll
        for (int py = 0; py < 2; ++py)
            #pragma unroll
            for (int px = 0; px < 2; ++px) {
                float4 a = g[(2*py)*4 + 2*px],     bb = g[(2*py)*4 + 2*px + 1];
                float4 c = g[(2*py+1)*4 + 2*px],   d  = g[(2*py+1)*4 + 2*px + 1];
                float4 s = make_float4(a.x+bb.x+c.x+d.x, a.y+bb.y+c.y+d.y,
                                       a.z+bb.z+c.z+d.z, a.w+bb.w+c.w+d.w);
                tot.x += s.x; tot.y += s.y; tot.z += s.z; tot.w += s.w;
                float4 o = make_float4(s.x*0.0625f, s.y*0.0625f, s.z*0.0625f, s.w*0.0625f);
                *(float4*)(f22 + (size_t)((b * 12 + sy * 2 + py) * 16 + sx * 2 + px) * 256 + ch4 * 4) = o;
            }
        float4 o = make_float4(tot.x*0.015625f, tot.y*0.015625f, tot.z*0.015625f, tot.w*0.015625f);
        *(float4*)(f23 + (size_t)((b * 6 + sy) * 8 + sx) * 256 + ch4 * 4) = o;
    }
}

// Main: block = (b, i, 8-pixel group); 4 waves = 4 levels.
// f1 tile (8px x 256ch) staged once in LDS by all 256 threads, then each
// wave: 8 lanes/pixel, lane owns 32 interleaved channels in 8 float4 regs.
// 3x3 candidate cells, 3-step shfl reduce, LDS-staged coalesced epilogue.
__global__ __launch_bounds__(256) void lookup_kernel(
        const float* __restrict__ feat1,   // (B,256,48,64) original layout
        const float* __restrict__ f20, const float* __restrict__ f21,
        const float* __restrict__ f22, const float* __restrict__ f23,
        const float* __restrict__ flow, float* __restrict__ out) {
    __shared__ float f1s[8 * 260];         // [px][256ch + 4 pad]
    __shared__ float dots[4][8][9];
    __shared__ float rawx[8], rawy[8];
    __shared__ int   mx0[4][8], my0[4][8];

    int bid = blockIdx.x;            // b*384 + i*8 + jg
    int b  = bid / 384;
    int r  = bid % 384;
    int i  = r >> 3;
    int jg = r & 7;
    int j0 = jg * 8;
    int tid = threadIdx.x;

    // Stage f1 tile: thread = channel; one 32B contiguous read.
    {
        const float* p = feat1 + ((size_t)(b * 256 + tid) * H8 + i) * W8 + j0;
        float4 a = *(const float4*)p;
        float4 c = *(const float4*)(p + 4);
        f1s[0*260 + tid] = a.x; f1s[1*260 + tid] = a.y;
        f1s[2*260 + tid] = a.z; f1s[3*260 + tid] = a.w;
        f1s[4*260 + tid] = c.x; f1s[5*260 + tid] = c.y;
        f1s[6*260 + tid] = c.z; f1s[7*260 + tid] = c.w;
    }
    __syncthreads();

    int k    = tid >> 6;             // wave id == pyramid level
    int lane = tid & 63;
    int p = lane >> 3;               // pixel in group (0..7)
    int l = lane & 7;                // channel-octant (owns quads q == l mod 8)
    int j = j0 + p;

    const float* f2lv[4] = {f20, f21, f22, f23};
    const float* f2k = f2lv[k];
    int hk = H8 >> k, wk = W8 >> k;
    float inv_sc = 1.0f / (float)(1 << k);
    float rx = (float)(wk - 1) / (512.0f * inv_sc);
    float ry = (float)(hk - 1) / (384.0f * inv_sc);

    float fy = flow[i * W8 + j];
    float fx = flow[SPAT + i * W8 + j];
    float base_x = ((float)j + fx) * inv_sc;
    float base_y = ((float)i + fy) * inv_sc;
    int x0lo = (int)floorf((base_x - 4.0f) * rx);
    int y0lo = (int)floorf((base_y - 4.0f) * ry);

    // f1 fragment: lane l owns channel quads {m*8+l}, m=0..7 (32 channels).
    float4 f1r[8];
    #pragma unroll
    for (int m = 0; m < 8; ++m)
        f1r[m] = *(const float4*)&f1s[p * 260 + (m * 8 + l) * 4];

    #pragma unroll
    for (int cy = 0; cy < 3; ++cy) {
        int y = y0lo + cy;
        #pragma unroll
        for (int cx = 0; cx < 3; ++cx) {
            int x = x0lo + cx;
            float acc = 0.0f;
            if (y >= 0 && y < hk && x >= 0 && x < wk) {
                const float* f2p = f2k + ((size_t)(b * hk + y) * wk + x) * 256 + l * 4;
                #pragma unroll
                for (int m = 0; m < 8; ++m) {
                    const float4 v = *(const float4*)(f2p + m * 32);
                    acc += v.x * f1r[m].x + v.y * f1r[m].y
                         + v.z * f1r[m].z + v.w * f1r[m].w;
                }
            }
            acc += __shfl_xor(acc, 1, 64);
            acc += __shfl_xor(acc, 2, 64);
            acc += __shfl_xor(acc, 4, 64);
            if (l == 0) dots[k][p][cy * 3 + cx] = acc;
        }
    }
    if (l == 0) {
        mx0[k][p] = x0lo;
        my0[k][p] = y0lo;
        if (k == 0) { rawx[p] = (float)j + fx; rawy[p] = (float)i + fy; }
    }
    __syncthreads();

    // Epilogue: 41*4*8 = 1312 outputs, p fastest -> coalesced runs.
    for (int t = tid; t < NL * 4 * 8; t += 256) {
        int p2 = t & 7;
        int lk = t >> 3;
        int kk = lk & 3;
        int ld = lk >> 2;
        float sc2 = (float)(1 << kk);
        float rx2 = (float)((W8 >> kk) - 1) / (512.0f / sc2);
        float ry2 = (float)((H8 >> kk) - 1) / (384.0f / sc2);
        float bx = rawx[p2] / sc2;
        float by = rawy[p2] / sc2;
        float px = (bx + c_xs[ld]) * rx2;
        float py = (by + c_ys[ld]) * ry2;
        float x0f = floorf(px), y0f = floorf(py);
        float tx = px - x0f, ty = py - y0f;
        int cx0 = (int)x0f - mx0[kk][p2];
        int cy0 = (int)y0f - my0[kk][p2];
        const float* dp = &dots[kk][p2][cy0 * 3 + cx0];
        float d00 = dp[0], d01 = dp[1], d10 = dp[3], d11 = dp[4];
        float v = d00 * (1.0f - tx) * (1.0f - ty) + d01 * tx * (1.0f - ty)
                + d10 * (1.0f - tx) * ty          + d11 * tx * ty;
        out[(size_t)((b * NL + ld) * 4 + kk) * SPAT + i * W8 + j0 + p2] = v * 0.0625f;
    }
}

extern "C" void kernel_launch(void* const* d_in, const int* in_sizes, int n_in,
                              void* d_out, int out_size, void* d_ws, size_t ws_size,
                              hipStream_t stream) {
    const float* feat1 = (const float*)d_in[0];
    const float* feat2 = (const float*)d_in[1];
    const float* flow  = (const float*)d_in[2];
    float* out = (float*)d_out;
    float* ws  = (float*)d_ws;

    float* f20 = ws;                   // 3,145,728 floats
    float* f21 = f20 + 3145728;        //   786,432
    float* f22 = f21 + 786432;         //   196,608
    float* f23 = f22 + 196608;         //    49,152   (total ~16.7 MB)

    hipLaunchKernelGGL(transpose_kernel, dim3(768), dim3(256), 0, stream, feat2, f20);
    hipLaunchKernelGGL(pyramid_kernel, dim3(192), dim3(256), 0, stream,
                       f20, f21, f22, f23);
    hipLaunchKernelGGL(lookup_kernel, dim3(1536), dim3(256), 0, stream,
                       feat1, f20, f21, f22, f23, flow, out);
}